// Round 13
// baseline (64.245 us; speedup 1.0000x reference)
//
#include <hip/hip_runtime.h>

#define KK 256
#define NCLS 18
#define MASK_BYTES_PER_BATCH (KK * KK)   // 65536

typedef unsigned long long ull;

// ---------------------------------------------------------------------------
// Phase 1 (r7-verified, verbatim): per-pair AFFINE transition planes.
// Word per (row i, lane): bit (4*p + q), pair q=j&3:
//   p0=A0 p1=A1 p2=B0 p3=B1 p4=isC p5=M0 p6=M1
// ws_sum[i] bit0 = row has any event.
// ---------------------------------------------------------------------------
__global__ __launch_bounds__(256)
void flags_kernel(const float* __restrict__ pc, const float* __restrict__ ps,
                  const float* __restrict__ ph, const float* __restrict__ sem,
                  const float* __restrict__ av,
                  unsigned char* __restrict__ ws_mask,
                  unsigned char* __restrict__ ws_sum,
                  float* __restrict__ out)
{
#pragma clang fp contract(off)
    const int blk = blockIdx.x;
    const int b   = blk >> 4;
    const int g   = blk & 15;
    const int tid = threadIdx.x;

    __shared__ float sd0[KK], sd1[KK], sd2[KK], sd3[KK], sd4[KK], sd5[KK];
    __shared__ float sp[KK], sn[KK], sc0[KK], sc1[KK], sc2[KK];
    __shared__ unsigned rowsum[16];

    const float* pcb  = pc  + (size_t)b * 3 * KK;
    const float* psb  = ps  + (size_t)b * 3 * KK;
    const float* phb  = ph  + (size_t)b * 2 * KK;
    const float* semb = sem + (size_t)b * (2 + NCLS) * KK;
    const float* avb  = av  + (size_t)b * KK * 3;
    float* outb       = out + (size_t)b * KK * 28;

    {   // stage proposal `tid`'s derived data (identical float exprs to ref)
        const int k = tid;
        const float c0 = avb[k*3+0] + pcb[0*KK + k];
        const float c1 = avb[k*3+1] + pcb[1*KK + k];
        const float c2 = avb[k*3+2] + pcb[2*KK + k];
        const float s0 = psb[0*KK + k], s1 = psb[1*KK + k], s2 = psb[2*KK + k];
        const float h1 = phb[1*KK + k];
        const float v0 = s0 * h1, v1 = s1, v2 = s2 * h1;
        sd0[k] = (v0 + c0) - fabsf(s0);
        sd1[k] = (v0 + c0);
        sd2[k] = (v1 + c1) - fabsf(s1);
        sd3[k] = (v1 + c1);
        sd4[k] = (v2 + c2) - fabsf(s2);
        sd5[k] = (v2 + c2);
        sp[k]  = semb[0*KK + k];
        sn[k]  = semb[1*KK + k];
        sc0[k] = c0; sc1[k] = c1; sc2[k] = c2;
    }
    if (tid < 16) rowsum[tid] = 0;
    __syncthreads();

    // consecutive lanes = consecutive ROWS (j-reads broadcast, i-reads stride-1)
    const int rl = tid & 15;          // local row 0..15
    const int i  = g * 16 + rl;       // global row
    const int j0 = (tid >> 4) * 16;   // 16 j's per thread

    const float piv = sp[i], niv = sn[i];
    const float di0 = sd0[i], di1 = sd1[i], di2 = sd2[i];
    const float di3 = sd3[i], di4 = sd4[i], di5 = sd5[i];
    const float ci0 = sc0[i], ci1 = sc1[i], ci2 = sc2[i];

    unsigned W[4] = {0u, 0u, 0u, 0u};
    bool evt = false;
#pragma unroll
    for (int t = 0; t < 16; ++t) {
        const int j = j0 + t;
        unsigned a0 = 1u, a1 = 1u, b0 = 0u, b1 = 0u, isC = 0u, mm0 = 0u, mm1 = 1u;
        if (j > i) {
            const float dx = ci0 - sc0[j];
            const float dy = ci1 - sc1[j];
            const float dz = ci2 - sc2[j];
            const float dist2 = dx*dx + dy*dy + dz*dz;
            if (dist2 < 9.0f) {
                const float e0 = sd0[j], e1 = sd1[j], e2 = sd2[j];
                const float e3 = sd3[j], e4 = sd4[j], e5 = sd5[j];
                const bool case0 = (e0 < di0) & (e1 > di1) & (e2 < di2)
                                 & (e3 > di3) & (e4 < di4) & (e5 > di5);
                const bool case1 = (e0 > di0) & (e1 < di1) & (e2 > di2)
                                 & (e3 < di3) & (e4 > di4) & (e5 < di5);
                if (case0) {
                    const unsigned tA0 = (piv < niv) ? 1u : 0u;
                    const unsigned tA1 = (niv < piv) ? 0u : 1u;
                    a0 = a1 = tA0 ^ tA1;
                    b0 = b1 = tA0;
                    evt = true;
                } else if (case1) {
                    const float pjv = sp[j], njv = sn[j];
                    mm0 = (pjv < njv) ? 1u : 0u;
                    mm1 = (njv < pjv) ? 0u : 1u;
                    evt = true;
                } else {
                    const bool ovx = ((e1 > di0) & (e1 < di1)) | ((di1 > e0) & (di1 < e1));
                    const bool ovy = ((e3 > di2) & (e3 < di3)) | ((di3 > e2) & (di3 < e3));
                    const bool ovz = ((e5 > di4) & (e5 < di5)) | ((di5 > e4) & (di5 < e5));
                    if (ovx & ovy & ovz) {
                        const float pjv = sp[j], njv = sn[j];
                        const unsigned c00 = (niv < njv) ? 1u : 0u;  // cond(0, bj=0)
                        const unsigned c10 = (piv < njv) ? 1u : 0u;  // cond(1, bj=0)
                        const unsigned c01 = (niv < pjv) ? 1u : 0u;  // cond(0, bj=1)
                        const unsigned c11 = (piv < pjv) ? 1u : 0u;  // cond(1, bj=1)
                        isC = 1u;
                        a0 = 1u ^ c00 ^ c10;  b0 = c00;
                        a1 = 1u ^ c01 ^ c11;  b1 = c01;
                        evt = true;
                    }
                }
            }
        }
        const unsigned s = a0 | (a1 << 4) | (b0 << 8) | (b1 << 12)
                         | (isC << 16) | (mm0 << 20) | (mm1 << 24);
        W[t >> 2] |= s << (t & 3);
    }

    uint4 w4;
    w4.x = W[0]; w4.y = W[1]; w4.z = W[2]; w4.w = W[3];
    *(uint4*)(ws_mask + (size_t)b * MASK_BYTES_PER_BATCH + i * KK + j0) = w4;

    if (evt) atomicOr(&rowsum[rl], 1u);

    // pass-through outputs for this block's k-slice [g*16, g*16+16)
    for (int s = tid; s < 16 * 28; s += 256) {
        const int kk = g * 16 + (s / 28);
        const int c  = s % 28;
        if (c == 8 || c == 9) continue;      // scores written by phase 2
        float val;
        if (c < 3)       val = (c == 0) ? sc0[kk] : ((c == 1) ? sc1[kk] : sc2[kk]);
        else if (c < 6)  val = psb[(c - 3) * KK + kk];
        else if (c < 8)  val = phb[(c - 6) * KK + kk];
        else             val = semb[(c - 8) * KK + kk];
        outb[(size_t)kk * 28 + c] = val;
    }

    __syncthreads();
    if (tid < 16) {
        ws_sum[b * KK + g * 16 + tid] = (unsigned char)rowsum[tid];
    }
}

// ---------------------------------------------------------------------------
// Phase 2: DUAL-BATCH scan. One wave handles two independent batches; the two
// row bodies (r7-verified, verbatim via macro) interleave in the scheduler to
// fill each other's dependency-stall cycles. 128 KB LDS (2 x 64 KB codes).
// ---------------------------------------------------------------------------
__global__ __launch_bounds__(64)
void suppress11_kernel(const float* __restrict__ sem,
                       const unsigned char* __restrict__ ws_mask,
                       const unsigned char* __restrict__ ws_sum,
                       float* __restrict__ out, int B)
{
    const int pb   = blockIdx.x;
    const int bA   = pb * 2;
    const int bBr  = pb * 2 + 1;
    const bool hasB = (bBr < B);
    const int bB   = hasB ? bBr : bA;
    const int lane = threadIdx.x;

    __shared__ unsigned s_mask[2 * KK * 64];   // 128 KB

    const float* sembA = sem + (size_t)bA * (2 + NCLS) * KK;
    const float* sembB = sem + (size_t)bB * (2 + NCLS) * KK;
    float* outbA = out + (size_t)bA * KK * 28;
    float* outbB = out + (size_t)bB * KK * 28;

    // stage codes for both batches: 16 x 16B in flight per sweep group
    const uint4* gmA = (const uint4*)(ws_mask + (size_t)bA * MASK_BYTES_PER_BATCH);
    const uint4* gmB = (const uint4*)(ws_mask + (size_t)bB * MASK_BYTES_PER_BATCH);
    uint4* smA = (uint4*)s_mask;
    uint4* smB = (uint4*)(s_mask + KK * 64);
    for (int so = 0; so < 64; so += 8) {
        uint4 v[8], w[8];
#pragma unroll
        for (int t = 0; t < 8; ++t) v[t] = gmA[(so + t) * 64 + lane];
#pragma unroll
        for (int t = 0; t < 8; ++t) w[t] = gmB[(so + t) * 64 + lane];
#pragma unroll
        for (int t = 0; t < 8; ++t) smA[(so + t) * 64 + lane] = v[t];
#pragma unroll
        for (int t = 0; t < 8; ++t) smB[(so + t) * 64 + lane] = w[t];
    }

    float pjA[4], njA[4], pjB[4], njB[4];
#pragma unroll
    for (int q = 0; q < 4; ++q) {
        const int k = lane * 4 + q;
        pjA[q] = sembA[0*KK + k];
        njA[q] = sembA[1*KK + k];
        pjB[q] = sembB[0*KK + k];
        njB[q] = sembB[1*KK + k];
    }

    // row-activity bitmaps via ballots
    const unsigned char* sbA = ws_sum + bA * KK;
    const unsigned char* sbB = ws_sum + bB * KK;
    const unsigned a0 = sbA[lane], a1 = sbA[64 + lane],
                   a2 = sbA[128 + lane], a3 = sbA[192 + lane];
    const unsigned e0 = sbB[lane], e1 = sbB[64 + lane],
                   e2 = sbB[128 + lane], e3 = sbB[192 + lane];
    const ull anyA0 = __ballot(a0 & 1u), anyA1 = __ballot(a1 & 1u),
              anyA2 = __ballot(a2 & 1u), anyA3 = __ballot(a3 & 1u);
    ull anyB0 = __ballot(e0 & 1u), anyB1 = __ballot(e1 & 1u),
        anyB2 = __ballot(e2 & 1u), anyB3 = __ballot(e3 & 1u);
    if (!hasB) { anyB0 = anyB1 = anyB2 = anyB3 = 0ull; }

    __syncthreads();   // staging complete

    unsigned bmaskA = 0, bmaskB = 0;
    const ull belowR = __builtin_bitreverse64((1ull << lane) - 1ull);

#define ROWBODY(i_, MW, BMV) { \
        const unsigned m = (MW); \
        const int slot = (i_) & 3, owner = (i_) >> 2; \
        const ull bsb = __ballot(((BMV >> slot) & 1u) != 0u); \
        const unsigned b_start = (unsigned)((bsb >> owner) & 1ull); \
        const unsigned A0n = m & 0xFu,         A1n = (m >> 4) & 0xFu; \
        const unsigned B0n = (m >> 8) & 0xFu,  B1n = (m >> 12) & 0xFu; \
        const unsigned isCn = (m >> 16) & 0xFu; \
        const unsigned M0n = (m >> 20) & 0xFu, M1n = (m >> 24) & 0xFu; \
        const unsigned bm = BMV; \
        const unsigned AV  = (A1n & bm) | (A0n & ~bm); \
        const unsigned BV  = (B1n & bm) | (B0n & ~bm); \
        const unsigned bmB = (M1n & bm) | (M0n & ~bm); \
        const unsigned F0s = isCn & ~BV; \
        const unsigned F1s = isCn & (AV ^ BV); \
        /* local affine exclusive prefix from entry 0 */ \
        const unsigned As = AV << 1; \
        const unsigned Bs = BV << 1; \
        const unsigned B2 = Bs ^ (As & (Bs << 1)); \
        const unsigned A2 = As & (As << 1); \
        const unsigned av0 = B2 ^ (A2 & (B2 << 2)); \
        const unsigned y  = As | 1u; \
        const unsigned z1 = y & ((y << 1) | 1u); \
        const unsigned pa = z1 & ((z1 << 2) | 3u); \
        const unsigned FS  = (AV & av0) ^ BV;   /* bit3 = tl(0) */ \
        const unsigned aTv = pa & AV;           /* bit3 = lane-total a */ \
        const ull b0m = __ballot((FS & 8u) != 0u); \
        const ull b1m = __ballot(((FS ^ aTv) & 8u) != 0u); \
        /* segmented-scan tail */ \
        const ull nm  = b0m & ~b1m; \
        const ull cm  = ~(b0m ^ b1m); \
        const ull cmr = __builtin_bitreverse64(cm); \
        const ull nmr = __builtin_bitreverse64(nm); \
        const ull Wr  = __builtin_bitreverse64(b0m); \
        const ull cbr = cmr & belowR; \
        const ull lb  = cbr & (0ull - cbr); \
        const unsigned vK = ((Wr & lb) != 0ull) ? 1u : 0u; \
        const ull betw = belowR & (lb - 1ull); \
        const unsigned par = (unsigned)__builtin_popcountll(nmr & betw) & 1u; \
        const unsigned excl = ((cbr != 0ull) ? vK : b_start) ^ par; \
        const ull lbA = cmr & (0ull - cmr); \
        const unsigned vKA = ((Wr & lbA) != 0ull) ? 1u : 0u; \
        const unsigned parA = (unsigned)__builtin_popcountll(nmr & (lbA - 1ull)) & 1u; \
        const unsigned bfin = ((cmr != 0ull) ? vKA : b_start) ^ parA; \
        /* C flips from per-step entry states; B effects via M planes */ \
        const unsigned Emask = (0u - excl) & 0xFu; \
        const unsigned sv = av0 ^ (pa & Emask); \
        const unsigned flips = (F1s & sv) | (F0s & ~sv); \
        unsigned nbm = bmB ^ flips; \
        const unsigned fixed = (nbm & ~(1u << slot)) | (bfin << slot); \
        BMV = (lane == owner) ? fixed : nbm; }

#define RUNCHUNK(W_, ANYA, ANYB, NROWS) \
    for (int bb = 0; bb < (NROWS); ++bb) { \
        const int i_ = ((W_) << 6) + bb; \
        const unsigned mnextA = s_mask[(i_ + 1) * 64 + lane]; \
        const unsigned mnextB = s_mask[KK * 64 + (i_ + 1) * 64 + lane]; \
        if (((ANYA) >> bb) & 1ull) ROWBODY(i_, mcurA, bmaskA) \
        if (((ANYB) >> bb) & 1ull) ROWBODY(i_, mcurB, bmaskB) \
        mcurA = mnextA; mcurB = mnextB; \
    }

    unsigned mcurA = s_mask[lane];            // row 0, batch A
    unsigned mcurB = s_mask[KK * 64 + lane];  // row 0, batch B
    RUNCHUNK(0, anyA0, anyB0, 64)
    RUNCHUNK(1, anyA1, anyB1, 64)
    RUNCHUNK(2, anyA2, anyB2, 64)
    RUNCHUNK(3, anyA3, anyB3, 63)

#undef RUNCHUNK
#undef ROWBODY

#pragma unroll
    for (int q = 0; q < 4; ++q) {
        const int k = lane * 4 + q;
        const unsigned bqA = (bmaskA >> q) & 1u;
        outbA[k*28 + 8] = bqA ? njA[q] : pjA[q];
        outbA[k*28 + 9] = bqA ? pjA[q] : njA[q];
    }
    if (hasB) {
#pragma unroll
        for (int q = 0; q < 4; ++q) {
            const int k = lane * 4 + q;
            const unsigned bqB = (bmaskB >> q) & 1u;
            outbB[k*28 + 8] = bqB ? njB[q] : pjB[q];
            outbB[k*28 + 9] = bqB ? pjB[q] : njB[q];
        }
    }
}

// ---------------------------------------------------------------------------
// Fallback (round-1 verified kernel) in case ws_size is too small.
// ---------------------------------------------------------------------------
__device__ __forceinline__ unsigned compose2(unsigned a, unsigned b) {
    unsigned r0 = (b >> (a & 1u)) & 1u;
    unsigned r1 = (b >> ((a >> 1) & 1u)) & 1u;
    return r0 | (r1 << 1u);
}

__global__ __launch_bounds__(64)
void proposal_suppress_kernel(const float* __restrict__ pc, const float* __restrict__ ps,
                              const float* __restrict__ ph, const float* __restrict__ sem,
                              const float* __restrict__ av, float* __restrict__ out)
{
#pragma clang fp contract(off)
    const int b    = blockIdx.x;
    const int lane = threadIdx.x;

    __shared__ float s_p[KK], s_n[KK], s_d[KK][6], s_c[KK][3];

    const float* pcb  = pc  + (size_t)b * 3 * KK;
    const float* psb  = ps  + (size_t)b * 3 * KK;
    const float* phb  = ph  + (size_t)b * 2 * KK;
    const float* semb = sem + (size_t)b * (2 + NCLS) * KK;
    const float* avb  = av  + (size_t)b * KK * 3;
    float* outb       = out + (size_t)b * KK * 28;

    float pj[4], nj[4], dj[4][6], cj[4][3];
    unsigned Ljm = 0, Gjm = 0, bmask = 0;

#pragma unroll
    for (int q = 0; q < 4; ++q) {
        const int k = lane * 4 + q;
        const float c0 = avb[k*3+0] + pcb[0*KK + k];
        const float c1 = avb[k*3+1] + pcb[1*KK + k];
        const float c2 = avb[k*3+2] + pcb[2*KK + k];
        const float s0 = psb[0*KK + k], s1 = psb[1*KK + k], s2 = psb[2*KK + k];
        const float h0 = phb[0*KK + k], h1 = phb[1*KK + k];
        const float v0 = s0 * h1, v1 = s1, v2 = s2 * h1;
        float d[6];
        d[0] = (v0 + c0) - fabsf(s0); d[1] = (v0 + c0);
        d[2] = (v1 + c1) - fabsf(s1); d[3] = (v1 + c1);
        d[4] = (v2 + c2) - fabsf(s2); d[5] = (v2 + c2);
        const float p = semb[0*KK + k];
        const float n = semb[1*KK + k];
        cj[q][0] = c0; cj[q][1] = c1; cj[q][2] = c2;
#pragma unroll
        for (int m = 0; m < 6; ++m) dj[q][m] = d[m];
        pj[q] = p; nj[q] = n;
        if (p < n) Ljm |= 1u << q;
        if (n < p) Gjm |= 1u << q;
        s_p[k] = p; s_n[k] = n;
#pragma unroll
        for (int m = 0; m < 6; ++m) s_d[k][m] = d[m];
        s_c[k][0] = c0; s_c[k][1] = c1; s_c[k][2] = c2;
        outb[k*28 + 0] = c0; outb[k*28 + 1] = c1; outb[k*28 + 2] = c2;
        outb[k*28 + 3] = s0; outb[k*28 + 4] = s1; outb[k*28 + 5] = s2;
        outb[k*28 + 6] = h0; outb[k*28 + 7] = h1;
#pragma unroll
        for (int cc = 0; cc < NCLS; ++cc)
            outb[k*28 + 10 + cc] = semb[(2 + cc)*KK + k];
    }
    __syncthreads();

    const unsigned ID = 2u;
    for (int i = 0; i < KK - 1; ++i) {
        const float piv = s_p[i], niv = s_n[i];
        const float di0 = s_d[i][0], di1 = s_d[i][1], di2 = s_d[i][2];
        const float di3 = s_d[i][3], di4 = s_d[i][4], di5 = s_d[i][5];
        const float ci0 = s_c[i][0], ci1 = s_c[i][1], ci2 = s_c[i][2];
        const unsigned tA = (piv < niv ? 1u : 0u) | ((niv < piv ? 0u : 1u) << 1);
        const int owner = i >> 2, slot = i & 3;

        unsigned tq[4];
        unsigned Cq = 0, cc0m = 0, cc1m = 0;
        unsigned tl = ID;
#pragma unroll
        for (int q = 0; q < 4; ++q) {
            const int j = lane * 4 + q;
            unsigned t = ID;
            if (j > i) {
                const float dx = ci0 - cj[q][0];
                const float dy = ci1 - cj[q][1];
                const float dz = ci2 - cj[q][2];
                const float dist2 = dx*dx + dy*dy + dz*dz;
                if (dist2 < 9.0f) {
                    const bool case0 = (dj[q][0] < di0) & (dj[q][1] > di1)
                                     & (dj[q][2] < di2) & (dj[q][3] > di3)
                                     & (dj[q][4] < di4) & (dj[q][5] > di5);
                    const bool case1 = (dj[q][0] > di0) & (dj[q][1] < di1)
                                     & (dj[q][2] > di2) & (dj[q][3] < di3)
                                     & (dj[q][4] > di4) & (dj[q][5] < di5);
                    if (case0) {
                        t = tA;
                    } else if (case1) {
                        const unsigned bj = (bmask >> q) & 1u;
                        const unsigned nb = bj ? (((Gjm >> q) & 1u) ? 0u : 1u)
                                               : (((Ljm >> q) & 1u) ? 1u : 0u);
                        bmask = (bmask & ~(1u << q)) | (nb << q);
                    } else {
                        const bool ovx = ((dj[q][1] > di0) & (dj[q][1] < di1))
                                       | ((di1 > dj[q][0]) & (di1 < dj[q][1]));
                        const bool ovy = ((dj[q][3] > di2) & (dj[q][3] < di3))
                                       | ((di3 > dj[q][2]) & (di3 < dj[q][3]));
                        const bool ovz = ((dj[q][5] > di4) & (dj[q][5] < di5))
                                       | ((di5 > dj[q][4]) & (di5 < dj[q][5]));
                        if (ovx & ovy & ovz) {
                            const unsigned bj = (bmask >> q) & 1u;
                            const float sj = bj ? pj[q] : nj[q];
                            const unsigned c0b = (niv < sj) ? 1u : 0u;
                            const unsigned c1b = (piv < sj) ? 1u : 0u;
                            t = c0b | ((c1b ^ 1u) << 1u);
                            Cq |= 1u << q; cc0m |= c0b << q; cc1m |= c1b << q;
                        }
                    }
                }
            }
            tq[q] = t;
            tl = compose2(tl, t);
        }

        const ull any = __ballot((tl != ID) || (Cq != 0));
        if (any == 0ull) continue;

        const unsigned b_start = (((unsigned)__shfl((int)bmask, owner, 64)) >> slot) & 1u;

        unsigned incl = tl;
#pragma unroll
        for (int off = 1; off < 64; off <<= 1) {
            const unsigned other = (unsigned)__shfl_up((int)incl, (unsigned)off, 64);
            if (lane >= off) incl = compose2(other, incl);
        }
        const unsigned total = (unsigned)__shfl((int)incl, 63, 64);
        const unsigned upv   = (unsigned)__shfl_up((int)incl, 1u, 64);
        const unsigned excl  = (lane == 0) ? ID : upv;

        unsigned cur = (excl >> b_start) & 1u;
#pragma unroll
        for (int q = 0; q < 4; ++q) {
            if ((Cq >> q) & 1u) {
                const unsigned cond = cur ? ((cc1m >> q) & 1u) : ((cc0m >> q) & 1u);
                if (!cond) bmask ^= (1u << q);
            }
            cur = (tq[q] >> cur) & 1u;
        }
        if (lane == owner) {
            const unsigned nbi = (total >> b_start) & 1u;
            bmask = (bmask & ~(1u << slot)) | (nbi << slot);
        }
    }

#pragma unroll
    for (int q = 0; q < 4; ++q) {
        const int k = lane * 4 + q;
        const unsigned bq = (bmask >> q) & 1u;
        outb[k*28 + 8] = bq ? nj[q] : pj[q];
        outb[k*28 + 9] = bq ? pj[q] : nj[q];
    }
}

extern "C" void kernel_launch(void* const* d_in, const int* in_sizes, int n_in,
                              void* d_out, int out_size, void* d_ws, size_t ws_size,
                              hipStream_t stream) {
    const float* pc  = (const float*)d_in[0];
    const float* ps  = (const float*)d_in[1];
    const float* ph  = (const float*)d_in[2];
    const float* sem = (const float*)d_in[3];
    const float* av  = (const float*)d_in[4];
    float* out = (float*)d_out;
    const int B = in_sizes[0] / (3 * KK);

    const size_t need = (size_t)B * MASK_BYTES_PER_BATCH + (size_t)B * KK;
    if (ws_size >= need) {
        unsigned char* wm   = (unsigned char*)d_ws;
        unsigned char* wsum = wm + (size_t)B * MASK_BYTES_PER_BATCH;
        flags_kernel<<<dim3(B * 16), dim3(256), 0, stream>>>(pc, ps, ph, sem, av, wm, wsum, out);
        suppress11_kernel<<<dim3((B + 1) / 2), dim3(64), 0, stream>>>(sem, wm, wsum, out, B);
    } else {
        proposal_suppress_kernel<<<dim3(B), dim3(64), 0, stream>>>(pc, ps, ph, sem, av, out);
    }
}

// Round 14
// 39.256 us; speedup vs baseline: 1.6366x; 1.6366x over previous
//
#include <hip/hip_runtime.h>

#define KK 256
#define NCLS 18
#define MASK_BYTES_PER_BATCH (KK * KK)   // 65536

typedef unsigned long long ull;

// ---------------------------------------------------------------------------
// Phase 1: per-pair AFFINE transition planes (r7-verified exprs/encoding),
// now at 1024 threads/block (16 waves/CU) for latency hiding: each thread
// computes ONE output word (4 pairs) instead of 16.
// Word per (row i, word jg): bit (4*p + q), pair j = jg*4+q:
//   p0=A0 p1=A1 p2=B0 p3=B1 p4=isC p5=M0 p6=M1
// ws_sum[i] bit0 = row has any event.
// ---------------------------------------------------------------------------
__global__ __launch_bounds__(1024)
void flags_kernel(const float* __restrict__ pc, const float* __restrict__ ps,
                  const float* __restrict__ ph, const float* __restrict__ sem,
                  const float* __restrict__ av,
                  unsigned char* __restrict__ ws_mask,
                  unsigned char* __restrict__ ws_sum,
                  float* __restrict__ out)
{
#pragma clang fp contract(off)
    const int blk = blockIdx.x;
    const int b   = blk >> 4;
    const int g   = blk & 15;
    const int tid = threadIdx.x;

    __shared__ float sd0[KK], sd1[KK], sd2[KK], sd3[KK], sd4[KK], sd5[KK];
    __shared__ float sp[KK], sn[KK], sc0[KK], sc1[KK], sc2[KK];
    __shared__ unsigned rowsum[16];

    const float* pcb  = pc  + (size_t)b * 3 * KK;
    const float* psb  = ps  + (size_t)b * 3 * KK;
    const float* phb  = ph  + (size_t)b * 2 * KK;
    const float* semb = sem + (size_t)b * (2 + NCLS) * KK;
    const float* avb  = av  + (size_t)b * KK * 3;
    float* outb       = out + (size_t)b * KK * 28;

    if (tid < KK) {   // stage proposal `tid`'s derived data (ref-identical)
        const int k = tid;
        const float c0 = avb[k*3+0] + pcb[0*KK + k];
        const float c1 = avb[k*3+1] + pcb[1*KK + k];
        const float c2 = avb[k*3+2] + pcb[2*KK + k];
        const float s0 = psb[0*KK + k], s1 = psb[1*KK + k], s2 = psb[2*KK + k];
        const float h1 = phb[1*KK + k];
        const float v0 = s0 * h1, v1 = s1, v2 = s2 * h1;
        sd0[k] = (v0 + c0) - fabsf(s0);
        sd1[k] = (v0 + c0);
        sd2[k] = (v1 + c1) - fabsf(s1);
        sd3[k] = (v1 + c1);
        sd4[k] = (v2 + c2) - fabsf(s2);
        sd5[k] = (v2 + c2);
        sp[k]  = semb[0*KK + k];
        sn[k]  = semb[1*KK + k];
        sc0[k] = c0; sc1[k] = c1; sc2[k] = c2;
    }
    if (tid < 16) rowsum[tid] = 0;
    __syncthreads();

    // consecutive lanes = consecutive ROWS (j-reads broadcast, conflict-free)
    const int rl = tid & 15;          // local row 0..15
    const int i  = g * 16 + rl;       // global row
    const int jg = tid >> 4;          // word index 0..63; j = jg*4 + t

    const float piv = sp[i], niv = sn[i];
    const float di0 = sd0[i], di1 = sd1[i], di2 = sd2[i];
    const float di3 = sd3[i], di4 = sd4[i], di5 = sd5[i];
    const float ci0 = sc0[i], ci1 = sc1[i], ci2 = sc2[i];

    unsigned Wv = 0;
    bool evt = false;
#pragma unroll
    for (int t = 0; t < 4; ++t) {
        const int j = jg * 4 + t;
        unsigned a0 = 1u, a1 = 1u, b0 = 0u, b1 = 0u, isC = 0u, mm0 = 0u, mm1 = 1u;
        if (j > i) {
            const float dx = ci0 - sc0[j];
            const float dy = ci1 - sc1[j];
            const float dz = ci2 - sc2[j];
            const float dist2 = dx*dx + dy*dy + dz*dz;
            if (dist2 < 9.0f) {
                const float e0 = sd0[j], e1 = sd1[j], e2 = sd2[j];
                const float e3 = sd3[j], e4 = sd4[j], e5 = sd5[j];
                const bool case0 = (e0 < di0) & (e1 > di1) & (e2 < di2)
                                 & (e3 > di3) & (e4 < di4) & (e5 > di5);
                const bool case1 = (e0 > di0) & (e1 < di1) & (e2 > di2)
                                 & (e3 < di3) & (e4 > di4) & (e5 < di5);
                if (case0) {
                    const unsigned tA0 = (piv < niv) ? 1u : 0u;
                    const unsigned tA1 = (niv < piv) ? 0u : 1u;
                    a0 = a1 = tA0 ^ tA1;
                    b0 = b1 = tA0;
                    evt = true;
                } else if (case1) {
                    const float pjv = sp[j], njv = sn[j];
                    mm0 = (pjv < njv) ? 1u : 0u;
                    mm1 = (njv < pjv) ? 0u : 1u;
                    evt = true;
                } else {
                    const bool ovx = ((e1 > di0) & (e1 < di1)) | ((di1 > e0) & (di1 < e1));
                    const bool ovy = ((e3 > di2) & (e3 < di3)) | ((di3 > e2) & (di3 < e3));
                    const bool ovz = ((e5 > di4) & (e5 < di5)) | ((di5 > e4) & (di5 < e5));
                    if (ovx & ovy & ovz) {
                        const float pjv = sp[j], njv = sn[j];
                        const unsigned c00 = (niv < njv) ? 1u : 0u;  // cond(0, bj=0)
                        const unsigned c10 = (piv < njv) ? 1u : 0u;  // cond(1, bj=0)
                        const unsigned c01 = (niv < pjv) ? 1u : 0u;  // cond(0, bj=1)
                        const unsigned c11 = (piv < pjv) ? 1u : 0u;  // cond(1, bj=1)
                        isC = 1u;
                        a0 = 1u ^ c00 ^ c10;  b0 = c00;
                        a1 = 1u ^ c01 ^ c11;  b1 = c01;
                        evt = true;
                    }
                }
            }
        }
        const unsigned s = a0 | (a1 << 4) | (b0 << 8) | (b1 << 12)
                         | (isC << 16) | (mm0 << 20) | (mm1 << 24);
        Wv |= s << t;
    }

    ((unsigned*)(ws_mask + (size_t)b * MASK_BYTES_PER_BATCH))[i * 64 + jg] = Wv;

    if (evt) atomicOr(&rowsum[rl], 1u);

    // pass-through outputs for this block's k-slice [g*16, g*16+16)
    for (int s = tid; s < 16 * 28; s += 1024) {
        const int kk = g * 16 + (s / 28);
        const int c  = s % 28;
        if (c == 8 || c == 9) continue;      // scores written by phase 2
        float val;
        if (c < 3)       val = (c == 0) ? sc0[kk] : ((c == 1) ? sc1[kk] : sc2[kk]);
        else if (c < 6)  val = psb[(c - 3) * KK + kk];
        else if (c < 8)  val = phb[(c - 6) * KK + kk];
        else             val = semb[(c - 8) * KK + kk];
        outb[(size_t)kk * 28 + c] = val;
    }

    __syncthreads();
    if (tid < 16) {
        ws_sum[b * KK + g * 16 + tid] = (unsigned char)rowsum[tid];
    }
}

// ---------------------------------------------------------------------------
// Phase 2 (r7 suppress7 VERBATIM): one wave per batch. Bulk LDS staging +
// distance-1 prefetch rotation; affine row body; ballot segmented-scan tail.
// ---------------------------------------------------------------------------
__global__ __launch_bounds__(64)
void suppress12_kernel(const float* __restrict__ sem,
                       const unsigned char* __restrict__ ws_mask,
                       const unsigned char* __restrict__ ws_sum,
                       float* __restrict__ out)
{
    const int b    = blockIdx.x;
    const int lane = threadIdx.x;

    __shared__ unsigned s_mask[KK * 64];   // 64 KB: linear copy of batch codes

    const float* semb = sem + (size_t)b * (2 + NCLS) * KK;
    float* outb       = out + (size_t)b * KK * 28;

    // stage codes: global -> LDS, 8 x 16B in flight per sweep group
    const uint4* gm = (const uint4*)(ws_mask + (size_t)b * MASK_BYTES_PER_BATCH);
    uint4* sm4 = (uint4*)s_mask;
    for (int so = 0; so < 64; so += 8) {
        uint4 v[8];
#pragma unroll
        for (int t = 0; t < 8; ++t) v[t] = gm[(so + t) * 64 + lane];
#pragma unroll
        for (int t = 0; t < 8; ++t) sm4[(so + t) * 64 + lane] = v[t];
    }

    float pj[4], nj[4];
#pragma unroll
    for (int q = 0; q < 4; ++q) {
        const int k = lane * 4 + q;
        pj[q] = semb[0*KK + k];
        nj[q] = semb[1*KK + k];
    }

    // row-activity bitmaps via ballots
    const unsigned char* sbp = ws_sum + b * KK;
    const unsigned sb0 = sbp[lane], sb1 = sbp[64 + lane],
                   sb2 = sbp[128 + lane], sb3 = sbp[192 + lane];
    const ull any0 = __ballot(sb0 & 1u);
    const ull any1 = __ballot(sb1 & 1u);
    const ull any2 = __ballot(sb2 & 1u);
    const ull any3 = __ballot(sb3 & 1u);

    __syncthreads();   // staging complete

    unsigned bmask = 0;
    const ull belowR = __builtin_bitreverse64((1ull << lane) - 1ull);

#define ROWBODY(i_) { \
        const unsigned m = mcur; \
        const int slot = (i_) & 3, owner = (i_) >> 2; \
        const ull bsb = __ballot(((bmask >> slot) & 1u) != 0u); \
        const unsigned b_start = (unsigned)((bsb >> owner) & 1ull); \
        const unsigned A0n = m & 0xFu,         A1n = (m >> 4) & 0xFu; \
        const unsigned B0n = (m >> 8) & 0xFu,  B1n = (m >> 12) & 0xFu; \
        const unsigned isCn = (m >> 16) & 0xFu; \
        const unsigned M0n = (m >> 20) & 0xFu, M1n = (m >> 24) & 0xFu; \
        const unsigned bm = bmask; \
        const unsigned AV  = (A1n & bm) | (A0n & ~bm); \
        const unsigned BV  = (B1n & bm) | (B0n & ~bm); \
        const unsigned bmB = (M1n & bm) | (M0n & ~bm); \
        const unsigned F0s = isCn & ~BV; \
        const unsigned F1s = isCn & (AV ^ BV); \
        /* local affine exclusive prefix from entry 0 */ \
        const unsigned As = AV << 1; \
        const unsigned Bs = BV << 1; \
        const unsigned B2 = Bs ^ (As & (Bs << 1)); \
        const unsigned A2 = As & (As << 1); \
        const unsigned av0 = B2 ^ (A2 & (B2 << 2)); \
        const unsigned y  = As | 1u; \
        const unsigned z1 = y & ((y << 1) | 1u); \
        const unsigned pa = z1 & ((z1 << 2) | 3u); \
        const unsigned FS  = (AV & av0) ^ BV;   /* bit3 = tl(0) */ \
        const unsigned aTv = pa & AV;           /* bit3 = lane-total a */ \
        const ull b0m = __ballot((FS & 8u) != 0u); \
        const ull b1m = __ballot(((FS ^ aTv) & 8u) != 0u); \
        /* segmented-scan tail */ \
        const ull nm  = b0m & ~b1m; \
        const ull cm  = ~(b0m ^ b1m); \
        const ull cmr = __builtin_bitreverse64(cm); \
        const ull nmr = __builtin_bitreverse64(nm); \
        const ull Wr  = __builtin_bitreverse64(b0m); \
        const ull cbr = cmr & belowR; \
        const ull lb  = cbr & (0ull - cbr); \
        const unsigned vK = ((Wr & lb) != 0ull) ? 1u : 0u; \
        const ull betw = belowR & (lb - 1ull); \
        const unsigned par = (unsigned)__builtin_popcountll(nmr & betw) & 1u; \
        const unsigned excl = ((cbr != 0ull) ? vK : b_start) ^ par; \
        const ull lbA = cmr & (0ull - cmr); \
        const unsigned vKA = ((Wr & lbA) != 0ull) ? 1u : 0u; \
        const unsigned parA = (unsigned)__builtin_popcountll(nmr & (lbA - 1ull)) & 1u; \
        const unsigned bfin = ((cmr != 0ull) ? vKA : b_start) ^ parA; \
        /* C flips from per-step entry states; B effects via M planes */ \
        const unsigned Emask = (0u - excl) & 0xFu; \
        const unsigned sv = av0 ^ (pa & Emask); \
        const unsigned flips = (F1s & sv) | (F0s & ~sv); \
        unsigned nbm = bmB ^ flips; \
        const unsigned fixed = (nbm & ~(1u << slot)) | (bfin << slot); \
        bmask = (lane == owner) ? fixed : nbm; }

#define RUNCHUNK(W_, ANY, NROWS) \
    for (int bb = 0; bb < (NROWS); ++bb) { \
        const int i_ = ((W_) << 6) + bb; \
        const unsigned mnext = s_mask[(i_ + 1) * 64 + lane]; \
        if (((ANY) >> bb) & 1ull) ROWBODY(i_) \
        mcur = mnext; \
    }

    unsigned mcur = s_mask[lane];   // row 0
    RUNCHUNK(0, any0, 64)
    RUNCHUNK(1, any1, 64)
    RUNCHUNK(2, any2, 64)
    RUNCHUNK(3, any3, 63)

#undef RUNCHUNK
#undef ROWBODY

#pragma unroll
    for (int q = 0; q < 4; ++q) {
        const int k = lane * 4 + q;
        const unsigned bq = (bmask >> q) & 1u;
        outb[k*28 + 8] = bq ? nj[q] : pj[q];
        outb[k*28 + 9] = bq ? pj[q] : nj[q];
    }
}

// ---------------------------------------------------------------------------
// Fallback (round-1 verified kernel) in case ws_size is too small.
// ---------------------------------------------------------------------------
__device__ __forceinline__ unsigned compose2(unsigned a, unsigned b) {
    unsigned r0 = (b >> (a & 1u)) & 1u;
    unsigned r1 = (b >> ((a >> 1) & 1u)) & 1u;
    return r0 | (r1 << 1u);
}

__global__ __launch_bounds__(64)
void proposal_suppress_kernel(const float* __restrict__ pc, const float* __restrict__ ps,
                              const float* __restrict__ ph, const float* __restrict__ sem,
                              const float* __restrict__ av, float* __restrict__ out)
{
#pragma clang fp contract(off)
    const int b    = blockIdx.x;
    const int lane = threadIdx.x;

    __shared__ float s_p[KK], s_n[KK], s_d[KK][6], s_c[KK][3];

    const float* pcb  = pc  + (size_t)b * 3 * KK;
    const float* psb  = ps  + (size_t)b * 3 * KK;
    const float* phb  = ph  + (size_t)b * 2 * KK;
    const float* semb = sem + (size_t)b * (2 + NCLS) * KK;
    const float* avb  = av  + (size_t)b * KK * 3;
    float* outb       = out + (size_t)b * KK * 28;

    float pj[4], nj[4], dj[4][6], cj[4][3];
    unsigned Ljm = 0, Gjm = 0, bmask = 0;

#pragma unroll
    for (int q = 0; q < 4; ++q) {
        const int k = lane * 4 + q;
        const float c0 = avb[k*3+0] + pcb[0*KK + k];
        const float c1 = avb[k*3+1] + pcb[1*KK + k];
        const float c2 = avb[k*3+2] + pcb[2*KK + k];
        const float s0 = psb[0*KK + k], s1 = psb[1*KK + k], s2 = psb[2*KK + k];
        const float h0 = phb[0*KK + k], h1 = phb[1*KK + k];
        const float v0 = s0 * h1, v1 = s1, v2 = s2 * h1;
        float d[6];
        d[0] = (v0 + c0) - fabsf(s0); d[1] = (v0 + c0);
        d[2] = (v1 + c1) - fabsf(s1); d[3] = (v1 + c1);
        d[4] = (v2 + c2) - fabsf(s2); d[5] = (v2 + c2);
        const float p = semb[0*KK + k];
        const float n = semb[1*KK + k];
        cj[q][0] = c0; cj[q][1] = c1; cj[q][2] = c2;
#pragma unroll
        for (int m = 0; m < 6; ++m) dj[q][m] = d[m];
        pj[q] = p; nj[q] = n;
        if (p < n) Ljm |= 1u << q;
        if (n < p) Gjm |= 1u << q;
        s_p[k] = p; s_n[k] = n;
#pragma unroll
        for (int m = 0; m < 6; ++m) s_d[k][m] = d[m];
        s_c[k][0] = c0; s_c[k][1] = c1; s_c[k][2] = c2;
        outb[k*28 + 0] = c0; outb[k*28 + 1] = c1; outb[k*28 + 2] = c2;
        outb[k*28 + 3] = s0; outb[k*28 + 4] = s1; outb[k*28 + 5] = s2;
        outb[k*28 + 6] = h0; outb[k*28 + 7] = h1;
#pragma unroll
        for (int cc = 0; cc < NCLS; ++cc)
            outb[k*28 + 10 + cc] = semb[(2 + cc)*KK + k];
    }
    __syncthreads();

    const unsigned ID = 2u;
    for (int i = 0; i < KK - 1; ++i) {
        const float piv = s_p[i], niv = s_n[i];
        const float di0 = s_d[i][0], di1 = s_d[i][1], di2 = s_d[i][2];
        const float di3 = s_d[i][3], di4 = s_d[i][4], di5 = s_d[i][5];
        const float ci0 = s_c[i][0], ci1 = s_c[i][1], ci2 = s_c[i][2];
        const unsigned tA = (piv < niv ? 1u : 0u) | ((niv < piv ? 0u : 1u) << 1);
        const int owner = i >> 2, slot = i & 3;

        unsigned tq[4];
        unsigned Cq = 0, cc0m = 0, cc1m = 0;
        unsigned tl = ID;
#pragma unroll
        for (int q = 0; q < 4; ++q) {
            const int j = lane * 4 + q;
            unsigned t = ID;
            if (j > i) {
                const float dx = ci0 - cj[q][0];
                const float dy = ci1 - cj[q][1];
                const float dz = ci2 - cj[q][2];
                const float dist2 = dx*dx + dy*dy + dz*dz;
                if (dist2 < 9.0f) {
                    const bool case0 = (dj[q][0] < di0) & (dj[q][1] > di1)
                                     & (dj[q][2] < di2) & (dj[q][3] > di3)
                                     & (dj[q][4] < di4) & (dj[q][5] > di5);
                    const bool case1 = (dj[q][0] > di0) & (dj[q][1] < di1)
                                     & (dj[q][2] > di2) & (dj[q][3] < di3)
                                     & (dj[q][4] > di4) & (dj[q][5] < di5);
                    if (case0) {
                        t = tA;
                    } else if (case1) {
                        const unsigned bj = (bmask >> q) & 1u;
                        const unsigned nb = bj ? (((Gjm >> q) & 1u) ? 0u : 1u)
                                               : (((Ljm >> q) & 1u) ? 1u : 0u);
                        bmask = (bmask & ~(1u << q)) | (nb << q);
                    } else {
                        const bool ovx = ((dj[q][1] > di0) & (dj[q][1] < di1))
                                       | ((di1 > dj[q][0]) & (di1 < dj[q][1]));
                        const bool ovy = ((dj[q][3] > di2) & (dj[q][3] < di3))
                                       | ((di3 > dj[q][2]) & (di3 < dj[q][3]));
                        const bool ovz = ((dj[q][5] > di4) & (dj[q][5] < di5))
                                       | ((di5 > dj[q][4]) & (di5 < dj[q][5]));
                        if (ovx & ovy & ovz) {
                            const unsigned bj = (bmask >> q) & 1u;
                            const float sj = bj ? pj[q] : nj[q];
                            const unsigned c0b = (niv < sj) ? 1u : 0u;
                            const unsigned c1b = (piv < sj) ? 1u : 0u;
                            t = c0b | ((c1b ^ 1u) << 1u);
                            Cq |= 1u << q; cc0m |= c0b << q; cc1m |= c1b << q;
                        }
                    }
                }
            }
            tq[q] = t;
            tl = compose2(tl, t);
        }

        const ull any = __ballot((tl != ID) || (Cq != 0));
        if (any == 0ull) continue;

        const unsigned b_start = (((unsigned)__shfl((int)bmask, owner, 64)) >> slot) & 1u;

        unsigned incl = tl;
#pragma unroll
        for (int off = 1; off < 64; off <<= 1) {
            const unsigned other = (unsigned)__shfl_up((int)incl, (unsigned)off, 64);
            if (lane >= off) incl = compose2(other, incl);
        }
        const unsigned total = (unsigned)__shfl((int)incl, 63, 64);
        const unsigned upv   = (unsigned)__shfl_up((int)incl, 1u, 64);
        const unsigned excl  = (lane == 0) ? ID : upv;

        unsigned cur = (excl >> b_start) & 1u;
#pragma unroll
        for (int q = 0; q < 4; ++q) {
            if ((Cq >> q) & 1u) {
                const unsigned cond = cur ? ((cc1m >> q) & 1u) : ((cc0m >> q) & 1u);
                if (!cond) bmask ^= (1u << q);
            }
            cur = (tq[q] >> cur) & 1u;
        }
        if (lane == owner) {
            const unsigned nbi = (total >> b_start) & 1u;
            bmask = (bmask & ~(1u << slot)) | (nbi << slot);
        }
    }

#pragma unroll
    for (int q = 0; q < 4; ++q) {
        const int k = lane * 4 + q;
        const unsigned bq = (bmask >> q) & 1u;
        outb[k*28 + 8] = bq ? nj[q] : pj[q];
        outb[k*28 + 9] = bq ? pj[q] : nj[q];
    }
}

extern "C" void kernel_launch(void* const* d_in, const int* in_sizes, int n_in,
                              void* d_out, int out_size, void* d_ws, size_t ws_size,
                              hipStream_t stream) {
    const float* pc  = (const float*)d_in[0];
    const float* ps  = (const float*)d_in[1];
    const float* ph  = (const float*)d_in[2];
    const float* sem = (const float*)d_in[3];
    const float* av  = (const float*)d_in[4];
    float* out = (float*)d_out;
    const int B = in_sizes[0] / (3 * KK);

    const size_t need = (size_t)B * MASK_BYTES_PER_BATCH + (size_t)B * KK;
    if (ws_size >= need) {
        unsigned char* wm   = (unsigned char*)d_ws;
        unsigned char* wsum = wm + (size_t)B * MASK_BYTES_PER_BATCH;
        flags_kernel<<<dim3(B * 16), dim3(1024), 0, stream>>>(pc, ps, ph, sem, av, wm, wsum, out);
        suppress12_kernel<<<dim3(B), dim3(64), 0, stream>>>(sem, wm, wsum, out);
    } else {
        proposal_suppress_kernel<<<dim3(B), dim3(64), 0, stream>>>(pc, ps, ph, sem, av, out);
    }
}